// Round 1
// baseline (3052.304 us; speedup 1.0000x reference)
//
#include <hip/hip_runtime.h>

#define NN 50000
#define NE 800000
#define D 64

__device__ __forceinline__ float lrelu(float x) { return x >= 0.0f ? x : 0.2f * x; }

__global__ __launch_bounds__(256) void egnn_edge_kernel(
    const float* __restrict__ h, const float* __restrict__ coord,
    const int* __restrict__ ei,
    const float* __restrict__ w1e, const float* __restrict__ b1e,
    const float* __restrict__ w2e, const float* __restrict__ b2e,
    float* __restrict__ edge_feat, float* __restrict__ agg)
{
    int e = blockIdx.x * 256 + threadIdx.x;
    if (e >= NE) return;
    int row = ei[e];
    int col = ei[NE + e];

    float dx = coord[row * 3 + 0] - coord[col * 3 + 0];
    float dy = coord[row * 3 + 1] - coord[col * 3 + 1];
    float dz = coord[row * 3 + 2] - coord[col * 3 + 2];
    float radial = dx * dx + dy * dy + dz * dz;

    // First layer: acc[j] = b1e[j] + radial*w1e[128][j] + sum_k h[row][k]*w1e[k][j] + h[col][k]*w1e[64+k][j]
    float acc[D];
#pragma unroll
    for (int j = 0; j < D; j++) acc[j] = fmaf(radial, w1e[128 * D + j], b1e[j]);

    const float4* hr = reinterpret_cast<const float4*>(h + (size_t)row * D);
    const float4* hc = reinterpret_cast<const float4*>(h + (size_t)col * D);

#pragma unroll
    for (int kk = 0; kk < 16; kk++) {
        float4 x = hr[kk];
        float xv[4] = {x.x, x.y, x.z, x.w};
#pragma unroll
        for (int c = 0; c < 4; c++) {
            const int k = kk * 4 + c;
#pragma unroll
            for (int j = 0; j < D; j++) acc[j] = fmaf(xv[c], w1e[k * D + j], acc[j]);
        }
    }
#pragma unroll
    for (int kk = 0; kk < 16; kk++) {
        float4 x = hc[kk];
        float xv[4] = {x.x, x.y, x.z, x.w};
#pragma unroll
        for (int c = 0; c < 4; c++) {
            const int k = 64 + kk * 4 + c;
#pragma unroll
            for (int j = 0; j < D; j++) acc[j] = fmaf(xv[c], w1e[k * D + j], acc[j]);
        }
    }
#pragma unroll
    for (int j = 0; j < D; j++) acc[j] = lrelu(acc[j]);

    // Second layer
    float acc2[D];
#pragma unroll
    for (int j = 0; j < D; j++) acc2[j] = b2e[j];
#pragma unroll
    for (int k = 0; k < D; k++) {
#pragma unroll
        for (int j = 0; j < D; j++) acc2[j] = fmaf(acc[k], w2e[k * D + j], acc2[j]);
    }
#pragma unroll
    for (int j = 0; j < D; j++) acc2[j] = lrelu(acc2[j]);

    // Write edge_feat (contiguous 256B per lane)
    float4* outp = reinterpret_cast<float4*>(edge_feat + (size_t)e * D);
#pragma unroll
    for (int q = 0; q < 16; q++)
        outp[q] = make_float4(acc2[4 * q], acc2[4 * q + 1], acc2[4 * q + 2], acc2[4 * q + 3]);

    // Scatter-add into agg[row]
    float* aggp = agg + (size_t)row * D;
#pragma unroll
    for (int j = 0; j < D; j++) atomicAdd(aggp + j, acc2[j]);
}

__global__ __launch_bounds__(256) void egnn_node_kernel(
    const float* __restrict__ h, const float* __restrict__ agg,
    const float* __restrict__ w1n, const float* __restrict__ b1n,
    const float* __restrict__ w2n, const float* __restrict__ b2n,
    const float* __restrict__ coord,
    float* __restrict__ h_out, float* __restrict__ coord_out)
{
    int n = blockIdx.x * 256 + threadIdx.x;
    if (n >= NN) return;

    float acc[D];
#pragma unroll
    for (int j = 0; j < D; j++) acc[j] = b1n[j];

    const float4* hp = reinterpret_cast<const float4*>(h + (size_t)n * D);
    const float4* ap = reinterpret_cast<const float4*>(agg + (size_t)n * D);

#pragma unroll
    for (int kk = 0; kk < 16; kk++) {
        float4 x = hp[kk];
        float xv[4] = {x.x, x.y, x.z, x.w};
#pragma unroll
        for (int c = 0; c < 4; c++) {
            const int k = kk * 4 + c;
#pragma unroll
            for (int j = 0; j < D; j++) acc[j] = fmaf(xv[c], w1n[k * D + j], acc[j]);
        }
    }
#pragma unroll
    for (int kk = 0; kk < 16; kk++) {
        float4 x = ap[kk];
        float xv[4] = {x.x, x.y, x.z, x.w};
#pragma unroll
        for (int c = 0; c < 4; c++) {
            const int k = 64 + kk * 4 + c;
#pragma unroll
            for (int j = 0; j < D; j++) acc[j] = fmaf(xv[c], w1n[k * D + j], acc[j]);
        }
    }
#pragma unroll
    for (int j = 0; j < D; j++) acc[j] = lrelu(acc[j]);

    float acc2[D];
#pragma unroll
    for (int j = 0; j < D; j++) acc2[j] = b2n[j];
#pragma unroll
    for (int k = 0; k < D; k++) {
#pragma unroll
        for (int j = 0; j < D; j++) acc2[j] = fmaf(acc[k], w2n[k * D + j], acc2[j]);
    }

    // Residual + store
    float4* op = reinterpret_cast<float4*>(h_out + (size_t)n * D);
#pragma unroll
    for (int q = 0; q < 16; q++) {
        float4 hv = hp[q];
        op[q] = make_float4(hv.x + acc2[4 * q], hv.y + acc2[4 * q + 1],
                            hv.z + acc2[4 * q + 2], hv.w + acc2[4 * q + 3]);
    }

    // coord passthrough
    coord_out[n * 3 + 0] = coord[n * 3 + 0];
    coord_out[n * 3 + 1] = coord[n * 3 + 1];
    coord_out[n * 3 + 2] = coord[n * 3 + 2];
}

extern "C" void kernel_launch(void* const* d_in, const int* in_sizes, int n_in,
                              void* d_out, int out_size, void* d_ws, size_t ws_size,
                              hipStream_t stream)
{
    const float* h     = (const float*)d_in[0];
    const float* coord = (const float*)d_in[1];
    const int*   ei    = (const int*)d_in[2];
    const float* w1e   = (const float*)d_in[3];
    const float* b1e   = (const float*)d_in[4];
    const float* w2e   = (const float*)d_in[5];
    const float* b2e   = (const float*)d_in[6];
    const float* w1n   = (const float*)d_in[7];
    const float* b1n   = (const float*)d_in[8];
    const float* w2n   = (const float*)d_in[9];
    const float* b2n   = (const float*)d_in[10];

    float* out       = (float*)d_out;
    float* h_out     = out;                    // [N, 64]
    float* coord_out = out + (size_t)NN * D;   // [N, 3]
    float* edge_feat = coord_out + (size_t)NN * 3;  // [E, 64]

    float* agg = (float*)d_ws;                 // [N, 64] scratch

    hipMemsetAsync(agg, 0, (size_t)NN * D * sizeof(float), stream);

    egnn_edge_kernel<<<(NE + 255) / 256, 256, 0, stream>>>(
        h, coord, ei, w1e, b1e, w2e, b2e, edge_feat, agg);

    egnn_node_kernel<<<(NN + 255) / 256, 256, 0, stream>>>(
        h, agg, w1n, b1n, w2n, b2n, coord, h_out, coord_out);
}

// Round 2
// 1067.648 us; speedup vs baseline: 2.8589x; 2.8589x over previous
//
#include <hip/hip_runtime.h>

#define NN 50000
#define NE 800000
#define D 64
#define SCAN_B 1024
#define NB ((NN + SCAN_B - 1) / SCAN_B)   // 49 scan blocks

__device__ __forceinline__ float lrelu(float x) { return x >= 0.0f ? x : 0.2f * x; }

// ---------- CSR build ----------
__global__ __launch_bounds__(256) void count_kernel(const int* __restrict__ ei,
                                                    int* __restrict__ counts)
{
    int e = blockIdx.x * 256 + threadIdx.x;
    if (e < NE) atomicAdd(&counts[ei[e]], 1);
}

__global__ __launch_bounds__(SCAN_B) void scan_block_kernel(const int* __restrict__ counts,
                                                            int* __restrict__ offs,
                                                            int* __restrict__ bsums)
{
    int i = blockIdx.x * SCAN_B + threadIdx.x;
    int v = (i < NN) ? counts[i] : 0;
    int lane = threadIdx.x & 63;
    int wid = threadIdx.x >> 6;
    int x = v;
#pragma unroll
    for (int d = 1; d < 64; d <<= 1) {
        int y = __shfl_up(x, d);
        if (lane >= d) x += y;
    }
    __shared__ int wsum[16];
    if (lane == 63) wsum[wid] = x;
    __syncthreads();
    if (wid == 0) {
        int s = (lane < 16) ? wsum[lane] : 0;
#pragma unroll
        for (int d = 1; d < 16; d <<= 1) {
            int y = __shfl_up(s, d);
            if (lane >= d) s += y;
        }
        if (lane < 16) wsum[lane] = s;
    }
    __syncthreads();
    int woff = (wid == 0) ? 0 : wsum[wid - 1];
    int excl = woff + x - v;           // exclusive scan within block
    if (i < NN) offs[i] = excl;
    if (threadIdx.x == 0) bsums[blockIdx.x] = wsum[15];  // block total
}

__global__ void scan_top_kernel(int* __restrict__ bsums)
{
    if (threadIdx.x == 0 && blockIdx.x == 0) {
        int run = 0;
        for (int b = 0; b < NB; b++) { int t = bsums[b]; bsums[b] = run; run += t; }
    }
}

__global__ __launch_bounds__(SCAN_B) void add_back_kernel(int* __restrict__ offs,
                                                          const int* __restrict__ bsums,
                                                          int* __restrict__ cursor)
{
    int i = blockIdx.x * SCAN_B + threadIdx.x;
    if (i < NN) {
        int o = offs[i] + bsums[blockIdx.x];
        offs[i] = o;
        cursor[i] = o;
    }
}

__global__ __launch_bounds__(256) void scatter_kernel(const int* __restrict__ ei,
                                                      int* __restrict__ cursor,
                                                      int* __restrict__ csr)
{
    int e = blockIdx.x * 256 + threadIdx.x;
    if (e < NE) {
        int pos = atomicAdd(&cursor[ei[e]], 1);
        csr[pos] = e;
    }
}

// ---------- edge MLP (no atomics) ----------
__global__ __launch_bounds__(256) void egnn_edge_kernel(
    const float* __restrict__ h, const float* __restrict__ coord,
    const int* __restrict__ ei,
    const float* __restrict__ w1e, const float* __restrict__ b1e,
    const float* __restrict__ w2e, const float* __restrict__ b2e,
    float* __restrict__ edge_feat)
{
    int e = blockIdx.x * 256 + threadIdx.x;
    if (e >= NE) return;
    int row = ei[e];
    int col = ei[NE + e];

    float dx = coord[row * 3 + 0] - coord[col * 3 + 0];
    float dy = coord[row * 3 + 1] - coord[col * 3 + 1];
    float dz = coord[row * 3 + 2] - coord[col * 3 + 2];
    float radial = dx * dx + dy * dy + dz * dz;

    float acc[D];
#pragma unroll
    for (int j = 0; j < D; j++) acc[j] = fmaf(radial, w1e[128 * D + j], b1e[j]);

    const float4* hr = reinterpret_cast<const float4*>(h + (size_t)row * D);
    const float4* hc = reinterpret_cast<const float4*>(h + (size_t)col * D);

#pragma unroll
    for (int kk = 0; kk < 16; kk++) {
        float4 x = hr[kk];
        float xv[4] = {x.x, x.y, x.z, x.w};
#pragma unroll
        for (int c = 0; c < 4; c++) {
            const int k = kk * 4 + c;
#pragma unroll
            for (int j = 0; j < D; j++) acc[j] = fmaf(xv[c], w1e[k * D + j], acc[j]);
        }
    }
#pragma unroll
    for (int kk = 0; kk < 16; kk++) {
        float4 x = hc[kk];
        float xv[4] = {x.x, x.y, x.z, x.w};
#pragma unroll
        for (int c = 0; c < 4; c++) {
            const int k = 64 + kk * 4 + c;
#pragma unroll
            for (int j = 0; j < D; j++) acc[j] = fmaf(xv[c], w1e[k * D + j], acc[j]);
        }
    }
#pragma unroll
    for (int j = 0; j < D; j++) acc[j] = lrelu(acc[j]);

    float acc2[D];
#pragma unroll
    for (int j = 0; j < D; j++) acc2[j] = b2e[j];
#pragma unroll
    for (int k = 0; k < D; k++) {
#pragma unroll
        for (int j = 0; j < D; j++) acc2[j] = fmaf(acc[k], w2e[k * D + j], acc2[j]);
    }
#pragma unroll
    for (int j = 0; j < D; j++) acc2[j] = lrelu(acc2[j]);

    float4* outp = reinterpret_cast<float4*>(edge_feat + (size_t)e * D);
#pragma unroll
    for (int q = 0; q < 16; q++)
        outp[q] = make_float4(acc2[4 * q], acc2[4 * q + 1], acc2[4 * q + 2], acc2[4 * q + 3]);
}

// ---------- aggregation: wave per node, coalesced gather ----------
__global__ __launch_bounds__(256) void agg_kernel(const float* __restrict__ edge_feat,
                                                  const int* __restrict__ csr,
                                                  const int* __restrict__ offs,
                                                  const int* __restrict__ counts,
                                                  float* __restrict__ agg)
{
    int w = (blockIdx.x * 256 + threadIdx.x) >> 6;
    int lane = threadIdx.x & 63;
    if (w >= NN) return;
    int start = offs[w];
    int cnt = counts[w];
    float s = 0.0f;
    int i = 0;
    while (i < cnt) {
        int chunk = min(cnt - i, 64);
        int eid = (lane < chunk) ? csr[start + i + lane] : 0;
        for (int t = 0; t < chunk; t++) {
            int e2 = __shfl(eid, t);
            s += edge_feat[(size_t)e2 * D + lane];
        }
        i += chunk;
    }
    agg[(size_t)w * D + lane] = s;
}

// ---------- node MLP ----------
__global__ __launch_bounds__(256) void egnn_node_kernel(
    const float* __restrict__ h, const float* __restrict__ agg,
    const float* __restrict__ w1n, const float* __restrict__ b1n,
    const float* __restrict__ w2n, const float* __restrict__ b2n,
    const float* __restrict__ coord,
    float* __restrict__ h_out, float* __restrict__ coord_out)
{
    int n = blockIdx.x * 256 + threadIdx.x;
    if (n >= NN) return;

    float acc[D];
#pragma unroll
    for (int j = 0; j < D; j++) acc[j] = b1n[j];

    const float4* hp = reinterpret_cast<const float4*>(h + (size_t)n * D);
    const float4* ap = reinterpret_cast<const float4*>(agg + (size_t)n * D);

#pragma unroll
    for (int kk = 0; kk < 16; kk++) {
        float4 x = hp[kk];
        float xv[4] = {x.x, x.y, x.z, x.w};
#pragma unroll
        for (int c = 0; c < 4; c++) {
            const int k = kk * 4 + c;
#pragma unroll
            for (int j = 0; j < D; j++) acc[j] = fmaf(xv[c], w1n[k * D + j], acc[j]);
        }
    }
#pragma unroll
    for (int kk = 0; kk < 16; kk++) {
        float4 x = ap[kk];
        float xv[4] = {x.x, x.y, x.z, x.w};
#pragma unroll
        for (int c = 0; c < 4; c++) {
            const int k = 64 + kk * 4 + c;
#pragma unroll
            for (int j = 0; j < D; j++) acc[j] = fmaf(xv[c], w1n[k * D + j], acc[j]);
        }
    }
#pragma unroll
    for (int j = 0; j < D; j++) acc[j] = lrelu(acc[j]);

    float acc2[D];
#pragma unroll
    for (int j = 0; j < D; j++) acc2[j] = b2n[j];
#pragma unroll
    for (int k = 0; k < D; k++) {
#pragma unroll
        for (int j = 0; j < D; j++) acc2[j] = fmaf(acc[k], w2n[k * D + j], acc2[j]);
    }

    float4* op = reinterpret_cast<float4*>(h_out + (size_t)n * D);
#pragma unroll
    for (int q = 0; q < 16; q++) {
        float4 hv = hp[q];
        op[q] = make_float4(hv.x + acc2[4 * q], hv.y + acc2[4 * q + 1],
                            hv.z + acc2[4 * q + 2], hv.w + acc2[4 * q + 3]);
    }

    coord_out[n * 3 + 0] = coord[n * 3 + 0];
    coord_out[n * 3 + 1] = coord[n * 3 + 1];
    coord_out[n * 3 + 2] = coord[n * 3 + 2];
}

extern "C" void kernel_launch(void* const* d_in, const int* in_sizes, int n_in,
                              void* d_out, int out_size, void* d_ws, size_t ws_size,
                              hipStream_t stream)
{
    const float* h     = (const float*)d_in[0];
    const float* coord = (const float*)d_in[1];
    const int*   ei    = (const int*)d_in[2];
    const float* w1e   = (const float*)d_in[3];
    const float* b1e   = (const float*)d_in[4];
    const float* w2e   = (const float*)d_in[5];
    const float* b2e   = (const float*)d_in[6];
    const float* w1n   = (const float*)d_in[7];
    const float* b1n   = (const float*)d_in[8];
    const float* w2n   = (const float*)d_in[9];
    const float* b2n   = (const float*)d_in[10];

    float* out       = (float*)d_out;
    float* h_out     = out;                         // [N, 64]
    float* coord_out = out + (size_t)NN * D;        // [N, 3]
    float* edge_feat = coord_out + (size_t)NN * 3;  // [E, 64]

    // workspace layout (all 4-byte elements)
    char* ws = (char*)d_ws;
    int* counts = (int*)ws;                 ws += sizeof(int) * NN;
    int* offs   = (int*)ws;                 ws += sizeof(int) * NN;
    int* cursor = (int*)ws;                 ws += sizeof(int) * NN;
    int* bsums  = (int*)ws;                 ws += sizeof(int) * 64;
    int* csr    = (int*)ws;                 ws += sizeof(int) * NE;
    float* agg  = (float*)ws;               ws += sizeof(float) * (size_t)NN * D;

    hipMemsetAsync(counts, 0, sizeof(int) * NN, stream);

    count_kernel<<<(NE + 255) / 256, 256, 0, stream>>>(ei, counts);
    scan_block_kernel<<<NB, SCAN_B, 0, stream>>>(counts, offs, bsums);
    scan_top_kernel<<<1, 64, 0, stream>>>(bsums);
    add_back_kernel<<<NB, SCAN_B, 0, stream>>>(offs, bsums, cursor);
    scatter_kernel<<<(NE + 255) / 256, 256, 0, stream>>>(ei, cursor, csr);

    egnn_edge_kernel<<<(NE + 255) / 256, 256, 0, stream>>>(
        h, coord, ei, w1e, b1e, w2e, b2e, edge_feat);

    agg_kernel<<<(NN * 64 + 255) / 256, 256, 0, stream>>>(
        edge_feat, csr, offs, counts, agg);

    egnn_node_kernel<<<(NN + 255) / 256, 256, 0, stream>>>(
        h, agg, w1n, b1n, w2n, b2n, coord, h_out, coord_out);
}

// Round 4
// 461.466 us; speedup vs baseline: 6.6144x; 2.3136x over previous
//
#include <hip/hip_runtime.h>

#define NN 50000
#define NE 800000
#define D 64
#define SCAN_B 1024
#define NB ((NN + SCAN_B - 1) / SCAN_B)   // 49 scan blocks

typedef __attribute__((ext_vector_type(8))) short bf16x8;
typedef __attribute__((ext_vector_type(4))) float f32x4;

__device__ __forceinline__ float lrelu(float x) { return x >= 0.0f ? x : 0.2f * x; }

__device__ __forceinline__ unsigned short f2bf(float f) {
    unsigned int x = __float_as_uint(f);
    unsigned int r = (x + 0x7fffu + ((x >> 16) & 1u)) >> 16;   // RNE
    return (unsigned short)r;
}

// ---------- prep: h -> bf16, weights -> transposed bf16 ----------
__global__ __launch_bounds__(256) void prep_h(const float* __restrict__ h,
                                              unsigned short* __restrict__ hb)
{
    int i = blockIdx.x * 256 + threadIdx.x;   // one float4 per thread
    if (i < NN * 16) {
        float4 v = ((const float4*)h)[i];
        ushort4 o;
        o.x = f2bf(v.x); o.y = f2bf(v.y); o.z = f2bf(v.z); o.w = f2bf(v.w);
        ((ushort4*)hb)[i] = o;
    }
}

__global__ __launch_bounds__(256) void prep_w(const float* __restrict__ w1e,
                                              const float* __restrict__ w2e,
                                              unsigned short* __restrict__ w1t,
                                              unsigned short* __restrict__ w2t)
{
    int t = blockIdx.x * 256 + threadIdx.x;
    if (t < 64 * 128) {                     // w1t[j][k] = w1e[k][j], k<128
        int j = t >> 7, k = t & 127;
        w1t[t] = f2bf(w1e[k * 64 + j]);
    } else if (t < 64 * 128 + 64 * 64) {    // w2t[j][k] = w2e[k][j]
        int t2 = t - 64 * 128;
        int j = t2 >> 6, k = t2 & 63;
        w2t[t2] = f2bf(w2e[k * 64 + j]);
    }
}

// ---------- CSR build ----------
__global__ __launch_bounds__(256) void count_kernel(const int* __restrict__ ei,
                                                    int* __restrict__ counts)
{
    int e = blockIdx.x * 256 + threadIdx.x;
    if (e < NE) atomicAdd(&counts[ei[e]], 1);
}

__global__ __launch_bounds__(SCAN_B) void scan_block_kernel(const int* __restrict__ counts,
                                                            int* __restrict__ offs,
                                                            int* __restrict__ bsums)
{
    int i = blockIdx.x * SCAN_B + threadIdx.x;
    int v = (i < NN) ? counts[i] : 0;
    int lane = threadIdx.x & 63;
    int wid = threadIdx.x >> 6;
    int x = v;
#pragma unroll
    for (int d = 1; d < 64; d <<= 1) {
        int y = __shfl_up(x, d);
        if (lane >= d) x += y;
    }
    __shared__ int wsum[16];
    if (lane == 63) wsum[wid] = x;
    __syncthreads();
    if (wid == 0) {
        int s = (lane < 16) ? wsum[lane] : 0;
#pragma unroll
        for (int d = 1; d < 16; d <<= 1) {
            int y = __shfl_up(s, d);
            if (lane >= d) s += y;
        }
        if (lane < 16) wsum[lane] = s;
    }
    __syncthreads();
    int woff = (wid == 0) ? 0 : wsum[wid - 1];
    int excl = woff + x - v;
    if (i < NN) offs[i] = excl;
    if (threadIdx.x == 0) bsums[blockIdx.x] = wsum[15];
}

__global__ void scan_top_kernel(int* __restrict__ bsums)
{
    if (threadIdx.x == 0 && blockIdx.x == 0) {
        int run = 0;
        for (int b = 0; b < NB; b++) { int t = bsums[b]; bsums[b] = run; run += t; }
    }
}

__global__ __launch_bounds__(SCAN_B) void add_back_kernel(int* __restrict__ offs,
                                                          const int* __restrict__ bsums,
                                                          int* __restrict__ cursor)
{
    int i = blockIdx.x * SCAN_B + threadIdx.x;
    if (i < NN) {
        int o = offs[i] + bsums[blockIdx.x];
        offs[i] = o;
        cursor[i] = o;
    }
}

__global__ __launch_bounds__(256) void scatter_kernel(const int* __restrict__ ei,
                                                      int* __restrict__ cursor,
                                                      int* __restrict__ csr)
{
    int e = blockIdx.x * 256 + threadIdx.x;
    if (e < NE) {
        int pos = atomicAdd(&cursor[ei[e]], 1);
        csr[pos] = e;
    }
}

// ---------- edge MLP via bf16 MFMA: 64 edges / block, 4 waves ----------
// A-frag fill: lane l elem i -> tile[l&15][(l>>4)*8 + i]
// B-frag fill: lane l elem i -> W[(l>>4)*8 + i][l&15]   (same k-map -> correct for any k-perm)
// C/D (m89):   col = lane&15, row = (lane>>4)*4 + reg
__global__ __launch_bounds__(256) void egnn_edge_mfma(
    const unsigned short* __restrict__ hb, const float* __restrict__ coord,
    const int* __restrict__ ei,
    const unsigned short* __restrict__ w1t, const float* __restrict__ b1e,
    const float* __restrict__ w1e,   // fp32, for last row w1e[128][j]
    const unsigned short* __restrict__ w2t, const float* __restrict__ b2e,
    float* __restrict__ edge_feat)
{
    __shared__ unsigned short Alds[64 * 128];   // 16 KB, XOR-swizzled rows of 256B
    __shared__ unsigned short Mlds[64 * 64];    // 8 KB, XOR-swizzled rows of 128B
    __shared__ float rad_lds[64];

    const int t = threadIdx.x, blk = blockIdx.x;
    const int lane = t & 63, wv = t >> 6;
    const int lo = lane & 15, hi = lane >> 4;

    // ---- B fragments (registers; small tables, L1-resident) ----
    bf16x8 b1f[4][4], b2f[2][4];
#pragma unroll
    for (int ct = 0; ct < 4; ct++) {
#pragma unroll
        for (int kc = 0; kc < 4; kc++)
            b1f[kc][ct] = *(const bf16x8*)(w1t + (ct * 16 + lo) * 128 + kc * 32 + hi * 8);
#pragma unroll
        for (int kc = 0; kc < 2; kc++)
            b2f[kc][ct] = *(const bf16x8*)(w2t + (ct * 16 + lo) * 64 + kc * 32 + hi * 8);
    }

    // ---- stage A: 4 threads per edge, 64B each, swizzled LDS ----
    const int ep = t >> 2, seg = t & 3;
    const int eg = blk * 64 + ep;
    const int node = (seg < 2) ? ei[eg] : ei[NE + eg];
    const uint4* src = (const uint4*)(hb + (size_t)node * 64 + (seg & 1) * 32);
    char* abase = (char*)Alds;
    const int rbase = ep * 256 + seg * 64;
    const int sw = (ep & 7) << 4;
#pragma unroll
    for (int c = 0; c < 4; c++) {
        uint4 v = src[c];
        *(uint4*)(abase + ((rbase + c * 16) ^ sw)) = v;
    }
    if (seg == 0) {
        int rn = node, cn = ei[NE + eg];
        float dx = coord[rn * 3 + 0] - coord[cn * 3 + 0];
        float dy = coord[rn * 3 + 1] - coord[cn * 3 + 1];
        float dz = coord[rn * 3 + 2] - coord[cn * 3 + 2];
        rad_lds[ep] = dx * dx + dy * dy + dz * dz;
    }
    __syncthreads();

    // ---- acc init: bias + radial * w1e[128][j] (fp32) ----
    f32x4 acc[4];
    float radv[4];
#pragma unroll
    for (int r = 0; r < 4; r++) radv[r] = rad_lds[wv * 16 + hi * 4 + r];
#pragma unroll
    for (int ct = 0; ct < 4; ct++) {
        float bj = b1e[ct * 16 + lo];
        float wl = w1e[128 * 64 + ct * 16 + lo];
#pragma unroll
        for (int r = 0; r < 4; r++) acc[ct][r] = fmaf(radv[r], wl, bj);
    }

    // ---- layer 1: 16 MFMA ----
#pragma unroll
    for (int kc = 0; kc < 4; kc++) {
        int row = wv * 16 + lo;
        bf16x8 a = *(bf16x8*)(abase + ((row * 256 + kc * 64 + hi * 16) ^ ((row & 7) << 4)));
#pragma unroll
        for (int ct = 0; ct < 4; ct++)
            acc[ct] = __builtin_amdgcn_mfma_f32_16x16x32_bf16(a, b1f[kc][ct], acc[ct], 0, 0, 0);
    }

    // ---- lrelu -> bf16 -> Mlds (wave-private rows) ----
    char* mbase = (char*)Mlds;
#pragma unroll
    for (int ct = 0; ct < 4; ct++) {
#pragma unroll
        for (int r = 0; r < 4; r++) {
            float v = lrelu(acc[ct][r]);
            int row = wv * 16 + hi * 4 + r;
            *(unsigned short*)(mbase + ((row * 128 + (ct * 16 + lo) * 2) ^ ((row & 7) << 4))) = f2bf(v);
        }
    }

    // ---- layer 2: 8 MFMA ----
    f32x4 acc2[4];
#pragma unroll
    for (int ct = 0; ct < 4; ct++) {
        float bj = b2e[ct * 16 + lo];
#pragma unroll
        for (int r = 0; r < 4; r++) acc2[ct][r] = bj;
    }
#pragma unroll
    for (int kc = 0; kc < 2; kc++) {
        int row = wv * 16 + lo;
        bf16x8 a = *(bf16x8*)(mbase + ((row * 128 + kc * 64 + hi * 16) ^ ((row & 7) << 4)));
#pragma unroll
        for (int ct = 0; ct < 4; ct++)
            acc2[ct] = __builtin_amdgcn_mfma_f32_16x16x32_bf16(a, b2f[kc][ct], acc2[ct], 0, 0, 0);
    }

    // ---- lrelu + store edge_feat fp32 ----
#pragma unroll
    for (int ct = 0; ct < 4; ct++) {
#pragma unroll
        for (int r = 0; r < 4; r++) {
            float v = lrelu(acc2[ct][r]);
            int er = blk * 64 + wv * 16 + hi * 4 + r;
            edge_feat[(size_t)er * 64 + ct * 16 + lo] = v;
        }
    }
}

// ---------- aggregation: wave per node, coalesced gather ----------
__global__ __launch_bounds__(256) void agg_kernel(const float* __restrict__ edge_feat,
                                                  const int* __restrict__ csr,
                                                  const int* __restrict__ offs,
                                                  const int* __restrict__ counts,
                                                  float* __restrict__ agg)
{
    int w = (blockIdx.x * 256 + threadIdx.x) >> 6;
    int lane = threadIdx.x & 63;
    if (w >= NN) return;
    int start = offs[w];
    int cnt = counts[w];
    float s = 0.0f;
    int i = 0;
    while (i < cnt) {
        int chunk = min(cnt - i, 64);
        int eid = (lane < chunk) ? csr[start + i + lane] : 0;
        for (int tt = 0; tt < chunk; tt++) {
            int e2 = __shfl(eid, tt);
            s += edge_feat[(size_t)e2 * D + lane];
        }
        i += chunk;
    }
    agg[(size_t)w * D + lane] = s;
}

// ---------- node MLP (fp32, known-good) ----------
__global__ __launch_bounds__(256) void egnn_node_kernel(
    const float* __restrict__ h, const float* __restrict__ agg,
    const float* __restrict__ w1n, const float* __restrict__ b1n,
    const float* __restrict__ w2n, const float* __restrict__ b2n,
    const float* __restrict__ coord,
    float* __restrict__ h_out, float* __restrict__ coord_out)
{
    int n = blockIdx.x * 256 + threadIdx.x;
    if (n >= NN) return;

    float acc[D];
#pragma unroll
    for (int j = 0; j < D; j++) acc[j] = b1n[j];

    const float4* hp = reinterpret_cast<const float4*>(h + (size_t)n * D);
    const float4* ap = reinterpret_cast<const float4*>(agg + (size_t)n * D);

#pragma unroll
    for (int kk = 0; kk < 16; kk++) {
        float4 x = hp[kk];
        float xv[4] = {x.x, x.y, x.z, x.w};
#pragma unroll
        for (int c = 0; c < 4; c++) {
            const int k = kk * 4 + c;
#pragma unroll
            for (int j = 0; j < D; j++) acc[j] = fmaf(xv[c], w1n[k * D + j], acc[j]);
        }
    }
#pragma unroll
    for (int kk = 0; kk < 16; kk++) {
        float4 x = ap[kk];
        float xv[4] = {x.x, x.y, x.z, x.w};
#pragma unroll
        for (int c = 0; c < 4; c++) {
            const int k = 64 + kk * 4 + c;
#pragma unroll
            for (int j = 0; j < D; j++) acc[j] = fmaf(xv[c], w1n[k * D + j], acc[j]);
        }
    }
#pragma unroll
    for (int j = 0; j < D; j++) acc[j] = lrelu(acc[j]);

    float acc2[D];
#pragma unroll
    for (int j = 0; j < D; j++) acc2[j] = b2n[j];
#pragma unroll
    for (int k = 0; k < D; k++) {
#pragma unroll
        for (int j = 0; j < D; j++) acc2[j] = fmaf(acc[k], w2n[k * D + j], acc2[j]);
    }

    float4* op = reinterpret_cast<float4*>(h_out + (size_t)n * D);
#pragma unroll
    for (int q = 0; q < 16; q++) {
        float4 hv = hp[q];
        op[q] = make_float4(hv.x + acc2[4 * q], hv.y + acc2[4 * q + 1],
                            hv.z + acc2[4 * q + 2], hv.w + acc2[4 * q + 3]);
    }

    coord_out[n * 3 + 0] = coord[n * 3 + 0];
    coord_out[n * 3 + 1] = coord[n * 3 + 1];
    coord_out[n * 3 + 2] = coord[n * 3 + 2];
}

extern "C" void kernel_launch(void* const* d_in, const int* in_sizes, int n_in,
                              void* d_out, int out_size, void* d_ws, size_t ws_size,
                              hipStream_t stream)
{
    const float* h     = (const float*)d_in[0];
    const float* coord = (const float*)d_in[1];
    const int*   ei    = (const int*)d_in[2];
    const float* w1e   = (const float*)d_in[3];
    const float* b1e   = (const float*)d_in[4];
    const float* w2e   = (const float*)d_in[5];
    const float* b2e   = (const float*)d_in[6];
    const float* w1n   = (const float*)d_in[7];
    const float* b1n   = (const float*)d_in[8];
    const float* w2n   = (const float*)d_in[9];
    const float* b2n   = (const float*)d_in[10];

    float* out       = (float*)d_out;
    float* h_out     = out;                         // [N, 64]
    float* coord_out = out + (size_t)NN * D;        // [N, 3]
    float* edge_feat = coord_out + (size_t)NN * 3;  // [E, 64]

    // workspace layout (16B-aligned chunks first)
    char* ws = (char*)d_ws;
    unsigned short* hb  = (unsigned short*)ws;  ws += sizeof(unsigned short) * (size_t)NN * D;  // 6.4 MB
    unsigned short* w1t = (unsigned short*)ws;  ws += sizeof(unsigned short) * 64 * 128;        // 16 KB
    unsigned short* w2t = (unsigned short*)ws;  ws += sizeof(unsigned short) * 64 * 64;         // 8 KB
    float* agg = (float*)ws;                    ws += sizeof(float) * (size_t)NN * D;           // 12.8 MB
    int* counts = (int*)ws;                     ws += sizeof(int) * NN;
    int* offs   = (int*)ws;                     ws += sizeof(int) * NN;
    int* cursor = (int*)ws;                     ws += sizeof(int) * NN;
    int* bsums  = (int*)ws;                     ws += sizeof(int) * 64;
    int* csr    = (int*)ws;                     ws += sizeof(int) * NE;                         // 3.2 MB

    hipMemsetAsync(counts, 0, sizeof(int) * NN, stream);

    prep_h<<<(NN * 16 + 255) / 256, 256, 0, stream>>>(h, hb);
    prep_w<<<(64 * 128 + 64 * 64 + 255) / 256, 256, 0, stream>>>(w1e, w2e, w1t, w2t);

    count_kernel<<<(NE + 255) / 256, 256, 0, stream>>>(ei, counts);
    scan_block_kernel<<<NB, SCAN_B, 0, stream>>>(counts, offs, bsums);
    scan_top_kernel<<<1, 64, 0, stream>>>(bsums);
    add_back_kernel<<<NB, SCAN_B, 0, stream>>>(offs, bsums, cursor);
    scatter_kernel<<<(NE + 255) / 256, 256, 0, stream>>>(ei, cursor, csr);

    egnn_edge_mfma<<<NE / 64, 256, 0, stream>>>(
        hb, coord, ei, w1t, b1e, w1e, w2t, b2e, edge_feat);

    agg_kernel<<<(NN * 64 + 255) / 256, 256, 0, stream>>>(
        edge_feat, csr, offs, counts, agg);

    egnn_node_kernel<<<(NN + 255) / 256, 256, 0, stream>>>(
        h, agg, w1n, b1n, w2n, b2n, coord, h_out, coord_out);
}

// Round 5
// 373.895 us; speedup vs baseline: 8.1635x; 1.2342x over previous
//
#include <hip/hip_runtime.h>

#define NN 50000
#define NE 800000
#define D 64
#define SCAN_B 1024
#define NB ((NN + SCAN_B - 1) / SCAN_B)   // 49 scan blocks
#define TILES 5
#define EPB (64 * TILES)                   // 320 edges/block, grid 2500 exact

typedef __attribute__((ext_vector_type(8))) short bf16x8;
typedef __attribute__((ext_vector_type(4))) float f32x4;

__device__ __forceinline__ float lrelu(float x) { return x >= 0.0f ? x : 0.2f * x; }

__device__ __forceinline__ unsigned short f2bf(float f) {
    unsigned int x = __float_as_uint(f);
    unsigned int r = (x + 0x7fffu + ((x >> 16) & 1u)) >> 16;   // RNE
    return (unsigned short)r;
}

// ---------- fused prep: h->bf16, w->bf16^T, degree count ----------
__global__ __launch_bounds__(256) void prep_count(const float* __restrict__ h,
                                                  unsigned short* __restrict__ hb,
                                                  const int* __restrict__ ei,
                                                  int* __restrict__ counts,
                                                  const float* __restrict__ w1e,
                                                  const float* __restrict__ w2e,
                                                  unsigned short* __restrict__ w1t,
                                                  unsigned short* __restrict__ w2t)
{
    int i = blockIdx.x * 256 + threadIdx.x;   // 800000 threads exactly
    // h conversion: 800000 float4s
    float4 v = ((const float4*)h)[i];
    ushort4 o;
    o.x = f2bf(v.x); o.y = f2bf(v.y); o.z = f2bf(v.z); o.w = f2bf(v.w);
    ((ushort4*)hb)[i] = o;
    // degree count
    atomicAdd(&counts[ei[i]], 1);
    // weight transpose (first 12288 threads)
    if (i < 64 * 128) {
        int j = i >> 7, k = i & 127;
        w1t[i] = f2bf(w1e[k * 64 + j]);
    } else if (i < 64 * 128 + 64 * 64) {
        int t2 = i - 64 * 128;
        int j = t2 >> 6, k = t2 & 63;
        w2t[t2] = f2bf(w2e[k * 64 + j]);
    }
}

// ---------- CSR build ----------
__global__ __launch_bounds__(SCAN_B) void scan_block_kernel(const int* __restrict__ counts,
                                                            int* __restrict__ offs,
                                                            int* __restrict__ bsums)
{
    int i = blockIdx.x * SCAN_B + threadIdx.x;
    int v = (i < NN) ? counts[i] : 0;
    int lane = threadIdx.x & 63;
    int wid = threadIdx.x >> 6;
    int x = v;
#pragma unroll
    for (int d = 1; d < 64; d <<= 1) {
        int y = __shfl_up(x, d);
        if (lane >= d) x += y;
    }
    __shared__ int wsum[16];
    if (lane == 63) wsum[wid] = x;
    __syncthreads();
    if (wid == 0) {
        int s = (lane < 16) ? wsum[lane] : 0;
#pragma unroll
        for (int d = 1; d < 16; d <<= 1) {
            int y = __shfl_up(s, d);
            if (lane >= d) s += y;
        }
        if (lane < 16) wsum[lane] = s;
    }
    __syncthreads();
    int woff = (wid == 0) ? 0 : wsum[wid - 1];
    int excl = woff + x - v;
    if (i < NN) offs[i] = excl;
    if (threadIdx.x == 0) bsums[blockIdx.x] = wsum[15];
}

__global__ void scan_top_kernel(int* __restrict__ bsums)
{
    if (threadIdx.x == 0 && blockIdx.x == 0) {
        int run = 0;
        for (int b = 0; b < NB; b++) { int t = bsums[b]; bsums[b] = run; run += t; }
    }
}

__global__ __launch_bounds__(SCAN_B) void add_back_kernel(int* __restrict__ offs,
                                                          const int* __restrict__ bsums,
                                                          int* __restrict__ cursor)
{
    int i = blockIdx.x * SCAN_B + threadIdx.x;
    if (i < NN) {
        int o = offs[i] + bsums[blockIdx.x];
        offs[i] = o;
        cursor[i] = o;
    }
}

__global__ __launch_bounds__(256) void scatter_kernel(const int* __restrict__ ei,
                                                      int* __restrict__ cursor,
                                                      int* __restrict__ csr)
{
    int e = blockIdx.x * 256 + threadIdx.x;
    if (e < NE) {
        int pos = atomicAdd(&cursor[ei[e]], 1);
        csr[pos] = e;
    }
}

// ---------- edge MLP via bf16 MFMA: 5 pipelined tiles of 64 edges / block ----------
// Per-wave col-stripe: wave wv computes output cols [wv*16, wv*16+16).
// A-frag: lane l elem i -> tile[l&15][(l>>4)*8+i]; B-frag same k-map on W^T.
// C/D (m89): col = lane&15, row = (lane>>4)*4 + reg.
__global__ __launch_bounds__(256) void egnn_edge_mfma(
    const unsigned short* __restrict__ hb, const float* __restrict__ coord,
    const int* __restrict__ ei,
    const unsigned short* __restrict__ w1t, const float* __restrict__ b1e,
    const float* __restrict__ w1e,   // fp32, for radial row w1e[128][j]
    const unsigned short* __restrict__ w2t, const float* __restrict__ b2e,
    float* __restrict__ edge_feat)
{
    __shared__ unsigned short Alds[64 * 128];   // 16 KB, XOR-swizzled 256B rows
    __shared__ unsigned short Mlds[64 * 64];    // 8 KB, XOR-swizzled 128B rows
    __shared__ float rad_lds[64];

    const int t = threadIdx.x, blk = blockIdx.x;
    const int lane = t & 63, wv = t >> 6;
    const int lo = lane & 15, hi = lane >> 4;

    // ---- per-wave B stripes (cols wv*16+lo) ----
    bf16x8 b1f[4], b2f[2];
#pragma unroll
    for (int kc = 0; kc < 4; kc++)
        b1f[kc] = *(const bf16x8*)(w1t + (wv * 16 + lo) * 128 + kc * 32 + hi * 8);
#pragma unroll
    for (int kc = 0; kc < 2; kc++)
        b2f[kc] = *(const bf16x8*)(w2t + (wv * 16 + lo) * 64 + kc * 32 + hi * 8);
    const float bj1 = b1e[wv * 16 + lo];
    const float wl1 = w1e[128 * 64 + wv * 16 + lo];
    const float bj2 = b2e[wv * 16 + lo];

    // ---- staging role: 4 threads per edge ----
    const int ep = t >> 2, seg = t & 3;
    char* abase = (char*)Alds;
    char* mbase = (char*)Mlds;
    const int sw = (ep & 7) << 4;
    const int rbase = ep * 256 + seg * 64;

    // ---- pipeline registers ----
    uint4 pre[4];
    float cr0, cr1, cr2, cc0, cc1, cc2;
    int nodeN, colN;

    // prologue: tile 0 data, tile 1 indices
    {
        int eg = blk * EPB + ep;
        int node = (seg < 2) ? ei[eg] : ei[NE + eg];
        int cnod = ei[NE + eg];
        const uint4* src = (const uint4*)(hb + (size_t)node * 64 + (seg & 1) * 32);
#pragma unroll
        for (int c = 0; c < 4; c++) pre[c] = src[c];
        cr0 = coord[node * 3 + 0]; cr1 = coord[node * 3 + 1]; cr2 = coord[node * 3 + 2];
        cc0 = coord[cnod * 3 + 0]; cc1 = coord[cnod * 3 + 1]; cc2 = coord[cnod * 3 + 2];
        int eg1 = blk * EPB + 64 + ep;
        nodeN = (seg < 2) ? ei[eg1] : ei[NE + eg1];
        colN = ei[NE + eg1];
    }

#pragma unroll
    for (int tl = 0; tl < TILES; tl++) {
        if (tl > 0) __syncthreads();          // protect A/M from prev readers
        // ---- stage current tile ----
#pragma unroll
        for (int c = 0; c < 4; c++)
            *(uint4*)(abase + ((rbase + c * 16) ^ sw)) = pre[c];
        if (seg == 0) {
            float dx = cr0 - cc0, dy = cr1 - cc1, dz = cr2 - cc2;
            rad_lds[ep] = dx * dx + dy * dy + dz * dz;
        }
        // ---- kick next tile's loads (hidden under MFMA below) ----
        if (tl + 1 < TILES) {
            int nn = nodeN, cn = colN;
            const uint4* src = (const uint4*)(hb + (size_t)nn * 64 + (seg & 1) * 32);
#pragma unroll
            for (int c = 0; c < 4; c++) pre[c] = src[c];
            cr0 = coord[nn * 3 + 0]; cr1 = coord[nn * 3 + 1]; cr2 = coord[nn * 3 + 2];
            cc0 = coord[cn * 3 + 0]; cc1 = coord[cn * 3 + 1]; cc2 = coord[cn * 3 + 2];
            if (tl + 2 < TILES) {
                int eg2 = blk * EPB + (tl + 2) * 64 + ep;
                nodeN = (seg < 2) ? ei[eg2] : ei[NE + eg2];
                colN = ei[NE + eg2];
            }
        }
        __syncthreads();                      // A + rad ready

        // ---- layer 1: 4 row-tiles x 4 kc ----
        f32x4 acc[4];
#pragma unroll
        for (int rt = 0; rt < 4; rt++) {
#pragma unroll
            for (int r = 0; r < 4; r++)
                acc[rt][r] = fmaf(rad_lds[rt * 16 + hi * 4 + r], wl1, bj1);
        }
#pragma unroll
        for (int kc = 0; kc < 4; kc++) {
#pragma unroll
            for (int rt = 0; rt < 4; rt++) {
                int row = rt * 16 + lo;
                bf16x8 a = *(bf16x8*)(abase + ((row * 256 + kc * 64 + hi * 16) ^ ((row & 7) << 4)));
                acc[rt] = __builtin_amdgcn_mfma_f32_16x16x32_bf16(a, b1f[kc], acc[rt], 0, 0, 0);
            }
        }
        // ---- lrelu -> bf16 -> Mlds ----
#pragma unroll
        for (int rt = 0; rt < 4; rt++) {
#pragma unroll
            for (int r = 0; r < 4; r++) {
                int row = rt * 16 + hi * 4 + r;
                *(unsigned short*)(mbase + ((row * 128 + (wv * 16 + lo) * 2) ^ ((row & 7) << 4))) =
                    f2bf(lrelu(acc[rt][r]));
            }
        }
        __syncthreads();                      // M ready (cross-wave stripes)

        // ---- layer 2 ----
        f32x4 acc2[4];
#pragma unroll
        for (int rt = 0; rt < 4; rt++) {
#pragma unroll
            for (int r = 0; r < 4; r++) acc2[rt][r] = bj2;
        }
#pragma unroll
        for (int kc = 0; kc < 2; kc++) {
#pragma unroll
            for (int rt = 0; rt < 4; rt++) {
                int row = rt * 16 + lo;
                bf16x8 a = *(bf16x8*)(mbase + ((row * 128 + kc * 64 + hi * 16) ^ ((row & 7) << 4)));
                acc2[rt] = __builtin_amdgcn_mfma_f32_16x16x32_bf16(a, b2f[kc], acc2[rt], 0, 0, 0);
            }
        }
        // ---- lrelu + store ----
#pragma unroll
        for (int rt = 0; rt < 4; rt++) {
#pragma unroll
            for (int r = 0; r < 4; r++) {
                int er = blk * EPB + tl * 64 + rt * 16 + hi * 4 + r;
                edge_feat[(size_t)er * 64 + wv * 16 + lo] = lrelu(acc2[rt][r]);
            }
        }
    }
}

// ---------- aggregation: wave per node, broadcast csr, 4 loads in flight ----------
__global__ __launch_bounds__(256) void agg_kernel(const float* __restrict__ edge_feat,
                                                  const int* __restrict__ csr,
                                                  const int* __restrict__ offs,
                                                  const int* __restrict__ counts,
                                                  float* __restrict__ agg)
{
    int w = (blockIdx.x * 256 + threadIdx.x) >> 6;
    int lane = threadIdx.x & 63;
    if (w >= NN) return;
    int start = offs[w];
    int cnt = counts[w];
    float s0 = 0.0f, s1 = 0.0f, s2 = 0.0f, s3 = 0.0f;
    int i = 0;
    for (; i + 4 <= cnt; i += 4) {
        int e0 = csr[start + i + 0];
        int e1 = csr[start + i + 1];
        int e2 = csr[start + i + 2];
        int e3 = csr[start + i + 3];
        s0 += edge_feat[(size_t)e0 * D + lane];
        s1 += edge_feat[(size_t)e1 * D + lane];
        s2 += edge_feat[(size_t)e2 * D + lane];
        s3 += edge_feat[(size_t)e3 * D + lane];
    }
    for (; i < cnt; i++) {
        int e0 = csr[start + i];
        s0 += edge_feat[(size_t)e0 * D + lane];
    }
    agg[(size_t)w * D + lane] = (s0 + s1) + (s2 + s3);
}

// ---------- node MLP (fp32; layer1 looped to keep I$ small, layer2 unrolled) ----------
__global__ __launch_bounds__(256) void egnn_node_kernel(
    const float* __restrict__ h, const float* __restrict__ agg,
    const float* __restrict__ w1n, const float* __restrict__ b1n,
    const float* __restrict__ w2n, const float* __restrict__ b2n,
    const float* __restrict__ coord,
    float* __restrict__ h_out, float* __restrict__ coord_out)
{
    int n = blockIdx.x * 256 + threadIdx.x;
    if (n >= NN) return;

    float acc[D];
#pragma unroll
    for (int j = 0; j < D; j++) acc[j] = b1n[j];

    const float4* hp = reinterpret_cast<const float4*>(h + (size_t)n * D);
    const float4* ap = reinterpret_cast<const float4*>(agg + (size_t)n * D);

    for (int kk = 0; kk < 16; kk++) {        // NOT unrolled: keep body ~1.5 KB
        float4 x = hp[kk];
        const float* wrow = w1n + (kk * 4) * D;
        float xv[4] = {x.x, x.y, x.z, x.w};
#pragma unroll
        for (int c = 0; c < 4; c++) {
#pragma unroll
            for (int j = 0; j < D; j++) acc[j] = fmaf(xv[c], wrow[c * D + j], acc[j]);
        }
    }
    for (int kk = 0; kk < 16; kk++) {
        float4 x = ap[kk];
        const float* wrow = w1n + (64 + kk * 4) * D;
        float xv[4] = {x.x, x.y, x.z, x.w};
#pragma unroll
        for (int c = 0; c < 4; c++) {
#pragma unroll
            for (int j = 0; j < D; j++) acc[j] = fmaf(xv[c], wrow[c * D + j], acc[j]);
        }
    }
#pragma unroll
    for (int j = 0; j < D; j++) acc[j] = lrelu(acc[j]);

    float acc2[D];
#pragma unroll
    for (int j = 0; j < D; j++) acc2[j] = b2n[j];
#pragma unroll
    for (int k = 0; k < D; k++) {            // unrolled: acc[k] must stay static (no scratch)
#pragma unroll
        for (int j = 0; j < D; j++) acc2[j] = fmaf(acc[k], w2n[k * D + j], acc2[j]);
    }

    float4* op = reinterpret_cast<float4*>(h_out + (size_t)n * D);
#pragma unroll
    for (int q = 0; q < 16; q++) {
        float4 hv = hp[q];
        op[q] = make_float4(hv.x + acc2[4 * q], hv.y + acc2[4 * q + 1],
                            hv.z + acc2[4 * q + 2], hv.w + acc2[4 * q + 3]);
    }

    coord_out[n * 3 + 0] = coord[n * 3 + 0];
    coord_out[n * 3 + 1] = coord[n * 3 + 1];
    coord_out[n * 3 + 2] = coord[n * 3 + 2];
}

extern "C" void kernel_launch(void* const* d_in, const int* in_sizes, int n_in,
                              void* d_out, int out_size, void* d_ws, size_t ws_size,
                              hipStream_t stream)
{
    const float* h     = (const float*)d_in[0];
    const float* coord = (const float*)d_in[1];
    const int*   ei    = (const int*)d_in[2];
    const float* w1e   = (const float*)d_in[3];
    const float* b1e   = (const float*)d_in[4];
    const float* w2e   = (const float*)d_in[5];
    const float* b2e   = (const float*)d_in[6];
    const float* w1n   = (const float*)d_in[7];
    const float* b1n   = (const float*)d_in[8];
    const float* w2n   = (const float*)d_in[9];
    const float* b2n   = (const float*)d_in[10];

    float* out       = (float*)d_out;
    float* h_out     = out;                         // [N, 64]
    float* coord_out = out + (size_t)NN * D;        // [N, 3]
    float* edge_feat = coord_out + (size_t)NN * 3;  // [E, 64]

    // workspace layout (16B-aligned chunks first)
    char* ws = (char*)d_ws;
    unsigned short* hb  = (unsigned short*)ws;  ws += sizeof(unsigned short) * (size_t)NN * D;  // 6.4 MB
    unsigned short* w1t = (unsigned short*)ws;  ws += sizeof(unsigned short) * 64 * 128;        // 16 KB
    unsigned short* w2t = (unsigned short*)ws;  ws += sizeof(unsigned short) * 64 * 64;         // 8 KB
    float* agg = (float*)ws;                    ws += sizeof(float) * (size_t)NN * D;           // 12.8 MB
    int* counts = (int*)ws;                     ws += sizeof(int) * NN;
    int* offs   = (int*)ws;                     ws += sizeof(int) * NN;
    int* cursor = (int*)ws;                     ws += sizeof(int) * NN;
    int* bsums  = (int*)ws;                     ws += sizeof(int) * 64;
    int* csr    = (int*)ws;                     ws += sizeof(int) * NE;                         // 3.2 MB

    hipMemsetAsync(counts, 0, sizeof(int) * NN, stream);

    prep_count<<<NE / 256, 256, 0, stream>>>(h, hb, ei, counts, w1e, w2e, w1t, w2t);

    scan_block_kernel<<<NB, SCAN_B, 0, stream>>>(counts, offs, bsums);
    scan_top_kernel<<<1, 64, 0, stream>>>(bsums);
    add_back_kernel<<<NB, SCAN_B, 0, stream>>>(offs, bsums, cursor);
    scatter_kernel<<<(NE + 255) / 256, 256, 0, stream>>>(ei, cursor, csr);

    egnn_edge_mfma<<<NE / EPB, 256, 0, stream>>>(
        hb, coord, ei, w1t, b1e, w1e, w2t, b2e, edge_feat);

    agg_kernel<<<(NN * 64 + 255) / 256, 256, 0, stream>>>(
        edge_feat, csr, offs, counts, agg);

    egnn_node_kernel<<<(NN + 255) / 256, 256, 0, stream>>>(
        h, agg, w1n, b1n, w2n, b2n, coord, h_out, coord_out);
}

// Round 6
// 320.710 us; speedup vs baseline: 9.5173x; 1.1658x over previous
//
#include <hip/hip_runtime.h>

#define NN 50000
#define NE 800000
#define D 64
#define SCAN_B 1024
#define NB ((NN + SCAN_B - 1) / SCAN_B)   // 49 scan blocks
#define TILES 5
#define EPB (64 * TILES)                   // 320 edges/block, grid 2500 exact

typedef __attribute__((ext_vector_type(8))) short bf16x8;
typedef __attribute__((ext_vector_type(4))) float f32x4;

__device__ __forceinline__ float lrelu(float x) { return x >= 0.0f ? x : 0.2f * x; }

__device__ __forceinline__ unsigned short f2bf(float f) {
    unsigned int x = __float_as_uint(f);
    unsigned int r = (x + 0x7fffu + ((x >> 16) & 1u)) >> 16;   // RNE
    return (unsigned short)r;
}

// ---------- fused prep: h->bf16, all 4 weights ->bf16^T, degree count ----------
__global__ __launch_bounds__(256) void prep_count(const float* __restrict__ h,
                                                  unsigned short* __restrict__ hb,
                                                  const int* __restrict__ ei,
                                                  int* __restrict__ counts,
                                                  const float* __restrict__ w1e,
                                                  const float* __restrict__ w2e,
                                                  const float* __restrict__ w1n,
                                                  const float* __restrict__ w2n,
                                                  unsigned short* __restrict__ w1t,
                                                  unsigned short* __restrict__ w2t,
                                                  unsigned short* __restrict__ w1nt,
                                                  unsigned short* __restrict__ w2nt)
{
    int i = blockIdx.x * 256 + threadIdx.x;   // 800000 threads exactly
    float4 v = ((const float4*)h)[i];         // guarded by grid: NN*16 = 800000
    ushort4 o;
    o.x = f2bf(v.x); o.y = f2bf(v.y); o.z = f2bf(v.z); o.w = f2bf(v.w);
    ((ushort4*)hb)[i] = o;
    atomicAdd(&counts[ei[i]], 1);
    if (i < 64 * 128) {                        // w1t[j][k] = w1e[k][j]
        int j = i >> 7, k = i & 127;
        w1t[i] = f2bf(w1e[k * 64 + j]);
    } else if (i < 12288) {                    // w2t[j][k] = w2e[k][j]
        int t2 = i - 8192;
        int j = t2 >> 6, k = t2 & 63;
        w2t[t2] = f2bf(w2e[k * 64 + j]);
    } else if (i < 20480) {                    // w1nt[j][k] = w1n[k][j]
        int t3 = i - 12288;
        int j = t3 >> 7, k = t3 & 127;
        w1nt[t3] = f2bf(w1n[k * 64 + j]);
    } else if (i < 24576) {                    // w2nt[j][k] = w2n[k][j]
        int t4 = i - 20480;
        int j = t4 >> 6, k = t4 & 63;
        w2nt[t4] = f2bf(w2n[k * 64 + j]);
    }
}

// ---------- CSR build ----------
__global__ __launch_bounds__(SCAN_B) void scan_block_kernel(const int* __restrict__ counts,
                                                            int* __restrict__ offs,
                                                            int* __restrict__ bsums)
{
    int i = blockIdx.x * SCAN_B + threadIdx.x;
    int v = (i < NN) ? counts[i] : 0;
    int lane = threadIdx.x & 63;
    int wid = threadIdx.x >> 6;
    int x = v;
#pragma unroll
    for (int d = 1; d < 64; d <<= 1) {
        int y = __shfl_up(x, d);
        if (lane >= d) x += y;
    }
    __shared__ int wsum[16];
    if (lane == 63) wsum[wid] = x;
    __syncthreads();
    if (wid == 0) {
        int s = (lane < 16) ? wsum[lane] : 0;
#pragma unroll
        for (int d = 1; d < 16; d <<= 1) {
            int y = __shfl_up(s, d);
            if (lane >= d) s += y;
        }
        if (lane < 16) wsum[lane] = s;
    }
    __syncthreads();
    int woff = (wid == 0) ? 0 : wsum[wid - 1];
    int excl = woff + x - v;
    if (i < NN) offs[i] = excl;
    if (threadIdx.x == 0) bsums[blockIdx.x] = wsum[15];
}

__global__ void scan_top_kernel(int* __restrict__ bsums)
{
    if (threadIdx.x == 0 && blockIdx.x == 0) {
        int run = 0;
        for (int b = 0; b < NB; b++) { int t = bsums[b]; bsums[b] = run; run += t; }
    }
}

__global__ __launch_bounds__(SCAN_B) void add_back_kernel(int* __restrict__ offs,
                                                          const int* __restrict__ bsums,
                                                          int* __restrict__ cursor)
{
    int i = blockIdx.x * SCAN_B + threadIdx.x;
    if (i < NN) {
        int o = offs[i] + bsums[blockIdx.x];
        offs[i] = o;
        cursor[i] = o;
    }
}

__global__ __launch_bounds__(256) void scatter_kernel(const int* __restrict__ ei,
                                                      int* __restrict__ cursor,
                                                      int* __restrict__ csr)
{
    int e = blockIdx.x * 256 + threadIdx.x;
    if (e < NE) {
        int pos = atomicAdd(&cursor[ei[e]], 1);
        csr[pos] = e;
    }
}

// ---------- edge MLP via bf16 MFMA: 5 pipelined tiles, coalesced LDS write-out ----------
__global__ __launch_bounds__(256) void egnn_edge_mfma(
    const unsigned short* __restrict__ hb, const float* __restrict__ coord,
    const int* __restrict__ ei,
    const unsigned short* __restrict__ w1t, const float* __restrict__ b1e,
    const float* __restrict__ w1e,   // fp32, for radial row w1e[128][j]
    const unsigned short* __restrict__ w2t, const float* __restrict__ b2e,
    float* __restrict__ edge_feat)
{
    __shared__ unsigned short Alds[64 * 128];   // 16 KB: A-tile, then reused as fp32 out-tile
    __shared__ unsigned short Mlds[64 * 64];    // 8 KB
    __shared__ float rad_lds[64];

    const int t = threadIdx.x, blk = blockIdx.x;
    const int lane = t & 63, wv = t >> 6;
    const int lo = lane & 15, hi = lane >> 4;

    bf16x8 b1f[4], b2f[2];
#pragma unroll
    for (int kc = 0; kc < 4; kc++)
        b1f[kc] = *(const bf16x8*)(w1t + (wv * 16 + lo) * 128 + kc * 32 + hi * 8);
#pragma unroll
    for (int kc = 0; kc < 2; kc++)
        b2f[kc] = *(const bf16x8*)(w2t + (wv * 16 + lo) * 64 + kc * 32 + hi * 8);
    const float bj1 = b1e[wv * 16 + lo];
    const float wl1 = w1e[128 * 64 + wv * 16 + lo];
    const float bj2 = b2e[wv * 16 + lo];

    const int ep = t >> 2, seg = t & 3;
    char* abase = (char*)Alds;
    char* mbase = (char*)Mlds;
    const int sw = (ep & 7) << 4;
    const int rbase = ep * 256 + seg * 64;
    // read-out role
    const int orow = t >> 2, ochunk = t & 3;
    const int osw = (orow & 7) << 4;

    uint4 pre[4];
    float cr0, cr1, cr2, cc0, cc1, cc2;
    int nodeN, colN;

    {
        int eg = blk * EPB + ep;
        int node = (seg < 2) ? ei[eg] : ei[NE + eg];
        int cnod = ei[NE + eg];
        const uint4* src = (const uint4*)(hb + (size_t)node * 64 + (seg & 1) * 32);
#pragma unroll
        for (int c = 0; c < 4; c++) pre[c] = src[c];
        cr0 = coord[node * 3 + 0]; cr1 = coord[node * 3 + 1]; cr2 = coord[node * 3 + 2];
        cc0 = coord[cnod * 3 + 0]; cc1 = coord[cnod * 3 + 1]; cc2 = coord[cnod * 3 + 2];
        int eg1 = blk * EPB + 64 + ep;
        nodeN = (seg < 2) ? ei[eg1] : ei[NE + eg1];
        colN = ei[NE + eg1];
    }

#pragma unroll
    for (int tl = 0; tl < TILES; tl++) {
        if (tl > 0) __syncthreads();          // prev read-out done -> Alds free
#pragma unroll
        for (int c = 0; c < 4; c++)
            *(uint4*)(abase + ((rbase + c * 16) ^ sw)) = pre[c];
        if (seg == 0) {
            float dx = cr0 - cc0, dy = cr1 - cc1, dz = cr2 - cc2;
            rad_lds[ep] = dx * dx + dy * dy + dz * dz;
        }
        if (tl + 1 < TILES) {                 // kick next tile's gathers
            int nn = nodeN, cn = colN;
            const uint4* src = (const uint4*)(hb + (size_t)nn * 64 + (seg & 1) * 32);
#pragma unroll
            for (int c = 0; c < 4; c++) pre[c] = src[c];
            cr0 = coord[nn * 3 + 0]; cr1 = coord[nn * 3 + 1]; cr2 = coord[nn * 3 + 2];
            cc0 = coord[cn * 3 + 0]; cc1 = coord[cn * 3 + 1]; cc2 = coord[cn * 3 + 2];
            if (tl + 2 < TILES) {
                int eg2 = blk * EPB + (tl + 2) * 64 + ep;
                nodeN = (seg < 2) ? ei[eg2] : ei[NE + eg2];
                colN = ei[NE + eg2];
            }
        }
        __syncthreads();                      // A + rad ready

        // layer 1
        f32x4 acc[4];
#pragma unroll
        for (int rt = 0; rt < 4; rt++) {
#pragma unroll
            for (int r = 0; r < 4; r++)
                acc[rt][r] = fmaf(rad_lds[rt * 16 + hi * 4 + r], wl1, bj1);
        }
#pragma unroll
        for (int kc = 0; kc < 4; kc++) {
#pragma unroll
            for (int rt = 0; rt < 4; rt++) {
                int row = rt * 16 + lo;
                bf16x8 a = *(bf16x8*)(abase + ((row * 256 + kc * 64 + hi * 16) ^ ((row & 7) << 4)));
                acc[rt] = __builtin_amdgcn_mfma_f32_16x16x32_bf16(a, b1f[kc], acc[rt], 0, 0, 0);
            }
        }
#pragma unroll
        for (int rt = 0; rt < 4; rt++) {
#pragma unroll
            for (int r = 0; r < 4; r++) {
                int row = rt * 16 + hi * 4 + r;
                *(unsigned short*)(mbase + ((row * 128 + (wv * 16 + lo) * 2) ^ ((row & 7) << 4))) =
                    f2bf(lrelu(acc[rt][r]));
            }
        }
        __syncthreads();                      // M ready; all Alds reads done too

        // layer 2
        f32x4 acc2[4];
#pragma unroll
        for (int rt = 0; rt < 4; rt++) {
#pragma unroll
            for (int r = 0; r < 4; r++) acc2[rt][r] = bj2;
        }
#pragma unroll
        for (int kc = 0; kc < 2; kc++) {
#pragma unroll
            for (int rt = 0; rt < 4; rt++) {
                int row = rt * 16 + lo;
                bf16x8 a = *(bf16x8*)(mbase + ((row * 128 + kc * 64 + hi * 16) ^ ((row & 7) << 4)));
                acc2[rt] = __builtin_amdgcn_mfma_f32_16x16x32_bf16(a, b2f[kc], acc2[rt], 0, 0, 0);
            }
        }
        // lrelu -> fp32 out-tile staged into Alds (swizzled)
#pragma unroll
        for (int rt = 0; rt < 4; rt++) {
#pragma unroll
            for (int r = 0; r < 4; r++) {
                int row = rt * 16 + hi * 4 + r;
                *(float*)(abase + ((row * 256 + (wv * 16 + lo) * 4) ^ ((row & 7) << 4))) =
                    lrelu(acc2[rt][r]);
            }
        }
        __syncthreads();                      // out-tile ready
        // coalesced write-out: 64 B per thread
        {
            uint4 o0 = *(uint4*)(abase + ((orow * 256 + ochunk * 64 +  0) ^ osw));
            uint4 o1 = *(uint4*)(abase + ((orow * 256 + ochunk * 64 + 16) ^ osw));
            uint4 o2 = *(uint4*)(abase + ((orow * 256 + ochunk * 64 + 32) ^ osw));
            uint4 o3 = *(uint4*)(abase + ((orow * 256 + ochunk * 64 + 48) ^ osw));
            uint4* dst = (uint4*)(edge_feat + (size_t)(blk * EPB + tl * 64 + orow) * 64 + ochunk * 16);
            dst[0] = o0; dst[1] = o1; dst[2] = o2; dst[3] = o3;
        }
    }
}

// ---------- fused aggregation + node MLP (MFMA) ----------
// Block = 64 consecutive nodes. Wave wv gathers agg for nodes wv*16..wv*16+15.
__global__ __launch_bounds__(256) void agg_node_mfma(
    const unsigned short* __restrict__ hb, const float* __restrict__ h,
    const float* __restrict__ coord,
    const float* __restrict__ edge_feat, const int* __restrict__ csr,
    const int* __restrict__ offs, const int* __restrict__ counts,
    const unsigned short* __restrict__ w1nt, const float* __restrict__ b1n,
    const unsigned short* __restrict__ w2nt, const float* __restrict__ b2n,
    float* __restrict__ h_out, float* __restrict__ coord_out)
{
    __shared__ unsigned short Alds[64 * 128];   // 16 KB: [h | agg] bf16, swizzled
    __shared__ unsigned short Mlds[64 * 64];    // 8 KB

    const int t = threadIdx.x, blk = blockIdx.x;
    const int lane = t & 63, wv = t >> 6;
    const int lo = lane & 15, hi = lane >> 4;
    const int nb = blk * 64;
    char* abase = (char*)Alds;
    char* mbase = (char*)Mlds;

    bf16x8 b1f[4], b2f[2];
#pragma unroll
    for (int kc = 0; kc < 4; kc++)
        b1f[kc] = *(const bf16x8*)(w1nt + (wv * 16 + lo) * 128 + kc * 32 + hi * 8);
#pragma unroll
    for (int kc = 0; kc < 2; kc++)
        b2f[kc] = *(const bf16x8*)(w2nt + (wv * 16 + lo) * 64 + kc * 32 + hi * 8);
    const float bj1 = b1n[wv * 16 + lo];
    const float bj2 = b2n[wv * 16 + lo];

    // stage hb rows -> A cols 0..63 (linear, coalesced)
    {
        int row = t >> 2, seg = t & 3;
        int n = min(nb + row, NN - 1);
        const uint4* src = (const uint4*)(hb + (size_t)n * 64 + seg * 16);
        int base = row * 256 + seg * 32;
        int swr = (row & 7) << 4;
        uint4 v0 = src[0], v1 = src[1];
        *(uint4*)(abase + ((base) ^ swr)) = v0;
        *(uint4*)(abase + ((base + 16) ^ swr)) = v1;
    }

    // gather-sum agg -> A cols 64..127 (lane = feature)
#pragma unroll 1
    for (int q = 0; q < 16; q++) {
        int n = nb + wv * 16 + q;
        int nc = min(n, NN - 1);
        int start = offs[nc];
        int cnt = counts[nc];
        float s0 = 0.0f, s1 = 0.0f, s2 = 0.0f, s3 = 0.0f;
        int i = 0;
        for (; i + 4 <= cnt; i += 4) {
            int e0 = csr[start + i + 0];
            int e1 = csr[start + i + 1];
            int e2 = csr[start + i + 2];
            int e3 = csr[start + i + 3];
            s0 += edge_feat[(size_t)e0 * D + lane];
            s1 += edge_feat[(size_t)e1 * D + lane];
            s2 += edge_feat[(size_t)e2 * D + lane];
            s3 += edge_feat[(size_t)e3 * D + lane];
        }
        for (; i < cnt; i++) {
            int e0 = csr[start + i];
            s0 += edge_feat[(size_t)e0 * D + lane];
        }
        float s = (s0 + s1) + (s2 + s3);
        int row = wv * 16 + q;
        *(unsigned short*)(abase + ((row * 256 + 128 + lane * 2) ^ ((row & 7) << 4))) = f2bf(s);
    }
    __syncthreads();

    // layer 1
    f32x4 acc[4];
#pragma unroll
    for (int rt = 0; rt < 4; rt++) {
#pragma unroll
        for (int r = 0; r < 4; r++) acc[rt][r] = bj1;
    }
#pragma unroll
    for (int kc = 0; kc < 4; kc++) {
#pragma unroll
        for (int rt = 0; rt < 4; rt++) {
            int row = rt * 16 + lo;
            bf16x8 a = *(bf16x8*)(abase + ((row * 256 + kc * 64 + hi * 16) ^ ((row & 7) << 4)));
            acc[rt] = __builtin_amdgcn_mfma_f32_16x16x32_bf16(a, b1f[kc], acc[rt], 0, 0, 0);
        }
    }
#pragma unroll
    for (int rt = 0; rt < 4; rt++) {
#pragma unroll
        for (int r = 0; r < 4; r++) {
            int row = rt * 16 + hi * 4 + r;
            *(unsigned short*)(mbase + ((row * 128 + (wv * 16 + lo) * 2) ^ ((row & 7) << 4))) =
                f2bf(lrelu(acc[rt][r]));
        }
    }
    __syncthreads();

    // layer 2 (no lrelu) + residual + store
    f32x4 acc2[4];
#pragma unroll
    for (int rt = 0; rt < 4; rt++) {
#pragma unroll
        for (int r = 0; r < 4; r++) acc2[rt][r] = bj2;
    }
#pragma unroll
    for (int kc = 0; kc < 2; kc++) {
#pragma unroll
        for (int rt = 0; rt < 4; rt++) {
            int row = rt * 16 + lo;
            bf16x8 a = *(bf16x8*)(mbase + ((row * 128 + kc * 64 + hi * 16) ^ ((row & 7) << 4)));
            acc2[rt] = __builtin_amdgcn_mfma_f32_16x16x32_bf16(a, b2f[kc], acc2[rt], 0, 0, 0);
        }
    }
#pragma unroll
    for (int rt = 0; rt < 4; rt++) {
#pragma unroll
        for (int r = 0; r < 4; r++) {
            int row = rt * 16 + hi * 4 + r;
            int n = nb + row;
            if (n < NN) {
                int c = wv * 16 + lo;
                h_out[(size_t)n * 64 + c] = h[(size_t)n * 64 + c] + acc2[rt][r];
            }
        }
    }

    // coord passthrough for this block's nodes
    if (t < 192) {
        int idx = nb * 3 + t;
        if (idx < NN * 3) coord_out[idx] = coord[idx];
    }
}

extern "C" void kernel_launch(void* const* d_in, const int* in_sizes, int n_in,
                              void* d_out, int out_size, void* d_ws, size_t ws_size,
                              hipStream_t stream)
{
    const float* h     = (const float*)d_in[0];
    const float* coord = (const float*)d_in[1];
    const int*   ei    = (const int*)d_in[2];
    const float* w1e   = (const float*)d_in[3];
    const float* b1e   = (const float*)d_in[4];
    const float* w2e   = (const float*)d_in[5];
    const float* b2e   = (const float*)d_in[6];
    const float* w1n   = (const float*)d_in[7];
    const float* b1n   = (const float*)d_in[8];
    const float* w2n   = (const float*)d_in[9];
    const float* b2n   = (const float*)d_in[10];

    float* out       = (float*)d_out;
    float* h_out     = out;                         // [N, 64]
    float* coord_out = out + (size_t)NN * D;        // [N, 3]
    float* edge_feat = coord_out + (size_t)NN * 3;  // [E, 64]

    char* ws = (char*)d_ws;
    unsigned short* hb   = (unsigned short*)ws;  ws += sizeof(unsigned short) * (size_t)NN * D;  // 6.4 MB
    unsigned short* w1t  = (unsigned short*)ws;  ws += sizeof(unsigned short) * 64 * 128;
    unsigned short* w2t  = (unsigned short*)ws;  ws += sizeof(unsigned short) * 64 * 64;
    unsigned short* w1nt = (unsigned short*)ws;  ws += sizeof(unsigned short) * 64 * 128;
    unsigned short* w2nt = (unsigned short*)ws;  ws += sizeof(unsigned short) * 64 * 64;
    int* counts = (int*)ws;                      ws += sizeof(int) * NN;
    int* offs   = (int*)ws;                      ws += sizeof(int) * NN;
    int* cursor = (int*)ws;                      ws += sizeof(int) * NN;
    int* bsums  = (int*)ws;                      ws += sizeof(int) * 64;
    int* csr    = (int*)ws;                      ws += sizeof(int) * NE;                         // 3.2 MB

    hipMemsetAsync(counts, 0, sizeof(int) * NN, stream);

    prep_count<<<NE / 256, 256, 0, stream>>>(h, hb, ei, counts,
                                             w1e, w2e, w1n, w2n, w1t, w2t, w1nt, w2nt);

    scan_block_kernel<<<NB, SCAN_B, 0, stream>>>(counts, offs, bsums);
    scan_top_kernel<<<1, 64, 0, stream>>>(bsums);
    add_back_kernel<<<NB, SCAN_B, 0, stream>>>(offs, bsums, cursor);
    scatter_kernel<<<(NE + 255) / 256, 256, 0, stream>>>(ei, cursor, csr);

    egnn_edge_mfma<<<NE / EPB, 256, 0, stream>>>(
        hb, coord, ei, w1t, b1e, w1e, w2t, b2e, edge_feat);

    agg_node_mfma<<<(NN + 63) / 64, 256, 0, stream>>>(
        hb, h, coord, edge_feat, csr, offs, counts,
        w1nt, b1n, w2nt, b2n, h_out, coord_out);
}

// Round 7
// 274.171 us; speedup vs baseline: 11.1328x; 1.1697x over previous
//
#include <hip/hip_runtime.h>

#define NN 50000
#define NE 800000
#define D 64
#define SCAN_B 1024
#define NB ((NN + SCAN_B - 1) / SCAN_B)   // 49 scan blocks
#define TILES 5
#define EPB (64 * TILES)                   // 320 edges/block, grid 2500 exact

typedef __attribute__((ext_vector_type(8))) short bf16x8;
typedef __attribute__((ext_vector_type(4))) float f32x4;

__device__ __forceinline__ float lrelu(float x) { return x >= 0.0f ? x : 0.2f * x; }

__device__ __forceinline__ unsigned short f2bf(float f) {
    unsigned int x = __float_as_uint(f);
    unsigned int r = (x + 0x7fffu + ((x >> 16) & 1u)) >> 16;   // RNE
    return (unsigned short)r;
}

// ---------- fused prep: h->bf16, all 4 weights ->bf16^T, degree count ----------
__global__ __launch_bounds__(256) void prep_count(const float* __restrict__ h,
                                                  unsigned short* __restrict__ hb,
                                                  const int* __restrict__ ei,
                                                  int* __restrict__ counts,
                                                  const float* __restrict__ w1e,
                                                  const float* __restrict__ w2e,
                                                  const float* __restrict__ w1n,
                                                  const float* __restrict__ w2n,
                                                  unsigned short* __restrict__ w1t,
                                                  unsigned short* __restrict__ w2t,
                                                  unsigned short* __restrict__ w1nt,
                                                  unsigned short* __restrict__ w2nt)
{
    int i = blockIdx.x * 256 + threadIdx.x;   // 800000 threads exactly
    float4 v = ((const float4*)h)[i];         // NN*16 == NE exactly
    ushort4 o;
    o.x = f2bf(v.x); o.y = f2bf(v.y); o.z = f2bf(v.z); o.w = f2bf(v.w);
    ((ushort4*)hb)[i] = o;
    atomicAdd(&counts[ei[i]], 1);
    if (i < 8192) {                            // w1t[j][k] = w1e[k][j]
        int j = i >> 7, k = i & 127;
        w1t[i] = f2bf(w1e[k * 64 + j]);
    } else if (i < 12288) {                    // w2t[j][k] = w2e[k][j]
        int t2 = i - 8192;
        int j = t2 >> 6, k = t2 & 63;
        w2t[t2] = f2bf(w2e[k * 64 + j]);
    } else if (i < 20480) {                    // w1nt[j][k] = w1n[k][j]
        int t3 = i - 12288;
        int j = t3 >> 7, k = t3 & 127;
        w1nt[t3] = f2bf(w1n[k * 64 + j]);
    } else if (i < 24576) {                    // w2nt[j][k] = w2n[k][j]
        int t4 = i - 20480;
        int j = t4 >> 6, k = t4 & 63;
        w2nt[t4] = f2bf(w2n[k * 64 + j]);
    }
}

// ---------- CSR build ----------
__global__ __launch_bounds__(SCAN_B) void scan_block_kernel(const int* __restrict__ counts,
                                                            int* __restrict__ offs,
                                                            int* __restrict__ bsums)
{
    int i = blockIdx.x * SCAN_B + threadIdx.x;
    int v = (i < NN) ? counts[i] : 0;
    int lane = threadIdx.x & 63;
    int wid = threadIdx.x >> 6;
    int x = v;
#pragma unroll
    for (int d = 1; d < 64; d <<= 1) {
        int y = __shfl_up(x, d);
        if (lane >= d) x += y;
    }
    __shared__ int wsum[16];
    if (lane == 63) wsum[wid] = x;
    __syncthreads();
    if (wid == 0) {
        int s = (lane < 16) ? wsum[lane] : 0;
#pragma unroll
        for (int d = 1; d < 16; d <<= 1) {
            int y = __shfl_up(s, d);
            if (lane >= d) s += y;
        }
        if (lane < 16) wsum[lane] = s;
    }
    __syncthreads();
    int woff = (wid == 0) ? 0 : wsum[wid - 1];
    int excl = woff + x - v;
    if (i < NN) offs[i] = excl;
    if (threadIdx.x == 0) bsums[blockIdx.x] = wsum[15];
}

__global__ void scan_top_kernel(int* __restrict__ bsums)
{
    if (threadIdx.x == 0 && blockIdx.x == 0) {
        int run = 0;
        for (int b = 0; b < NB; b++) { int t = bsums[b]; bsums[b] = run; run += t; }
    }
}

__global__ __launch_bounds__(SCAN_B) void add_back_kernel(int* __restrict__ offs,
                                                          const int* __restrict__ bsums,
                                                          int* __restrict__ cursor)
{
    int i = blockIdx.x * SCAN_B + threadIdx.x;
    if (i < NN) {
        int o = offs[i] + bsums[blockIdx.x];
        offs[i] = o;
        cursor[i] = o;
    }
}

__global__ __launch_bounds__(256) void scatter_kernel(const int* __restrict__ ei,
                                                      int* __restrict__ cursor,
                                                      int* __restrict__ csr,
                                                      int* __restrict__ rowpos)
{
    int e = blockIdx.x * 256 + threadIdx.x;
    if (e < NE) {
        int r = ei[e];
        int pos = atomicAdd(&cursor[r], 1);
        csr[pos] = e;
        rowpos[pos] = r;
    }
}

// ---------- edge MLP via bf16 MFMA, CSR order, fused partial aggregation ----------
// pos p = blk*EPB + tl*64 + i; edge e = csr[p]; row = rowpos[p] (nondecreasing).
// A row i = [ hb[row] 128B | hb[col] 128B ], XOR-swizzled. Wave wv = out cols [wv*16,+16).
__global__ __launch_bounds__(256) void egnn_edge_mfma(
    const unsigned short* __restrict__ hb, const float* __restrict__ coord,
    const int* __restrict__ ei,
    const int* __restrict__ csr, const int* __restrict__ rowpos,
    const unsigned short* __restrict__ w1t, const float* __restrict__ b1e,
    const float* __restrict__ w1e,   // fp32, for radial row w1e[128][j]
    const unsigned short* __restrict__ w2t, const float* __restrict__ b2e,
    float* __restrict__ edge_feat, float* __restrict__ agg)
{
    __shared__ unsigned short Alds[64 * 128];   // 16 KB: A-tile, reused as fp32 out-tile
    __shared__ unsigned short Mlds[64 * 64];    // 8 KB
    __shared__ float rad_lds[64];
    __shared__ int rl_lds[64];                  // row id per pos-slot

    const int t = threadIdx.x, blk = blockIdx.x;
    const int lane = t & 63, wv = t >> 6;
    const int lo = lane & 15, hi = lane >> 4;

    bf16x8 b1f[4], b2f[2];
#pragma unroll
    for (int kc = 0; kc < 4; kc++)
        b1f[kc] = *(const bf16x8*)(w1t + (wv * 16 + lo) * 128 + kc * 32 + hi * 8);
#pragma unroll
    for (int kc = 0; kc < 2; kc++)
        b2f[kc] = *(const bf16x8*)(w2t + (wv * 16 + lo) * 64 + kc * 32 + hi * 8);
    const float bj1 = b1e[wv * 16 + lo];
    const float wl1 = w1e[128 * 64 + wv * 16 + lo];
    const float bj2 = b2e[wv * 16 + lo];

    const int ip = t >> 2, seg = t & 3;
    char* abase = (char*)Alds;
    char* mbase = (char*)Mlds;
    const int sw = (ip & 7) << 4;
    const int rbase = ip * 256 + seg * 64;

    uint4 pre[4];
    int rowC, colC, rowN, colN;

    {   // prologue: tile0 data + tile1 ids
        int p0 = blk * EPB + ip;
        int e0 = csr[p0];
        rowC = rowpos[p0];
        colC = ei[NE + e0];
        int nd = (seg < 2) ? rowC : colC;
        const uint4* src = (const uint4*)(hb + (size_t)nd * 64 + (seg & 1) * 32);
#pragma unroll
        for (int c = 0; c < 4; c++) pre[c] = src[c];
        int p1 = p0 + 64;
        int e1 = csr[p1];
        rowN = rowpos[p1];
        colN = ei[NE + e1];
    }

#pragma unroll
    for (int tl = 0; tl < TILES; tl++) {
        if (tl > 0) __syncthreads();          // prev tile's read-out/scan done
#pragma unroll
        for (int c = 0; c < 4; c++)
            *(uint4*)(abase + ((rbase + c * 16) ^ sw)) = pre[c];
        if (seg == 0) {
            float dx = coord[rowC * 3 + 0] - coord[colC * 3 + 0];
            float dy = coord[rowC * 3 + 1] - coord[colC * 3 + 1];
            float dz = coord[rowC * 3 + 2] - coord[colC * 3 + 2];
            rad_lds[ip] = dx * dx + dy * dy + dz * dz;
        }
        if (seg == 1) rl_lds[ip] = rowC;
        if (tl + 1 < TILES) {                 // kick next tile's hb gathers
            int nd = (seg < 2) ? rowN : colN;
            const uint4* src = (const uint4*)(hb + (size_t)nd * 64 + (seg & 1) * 32);
#pragma unroll
            for (int c = 0; c < 4; c++) pre[c] = src[c];
            rowC = rowN; colC = colN;
            if (tl + 2 < TILES) {
                int p2 = blk * EPB + (tl + 2) * 64 + ip;
                int e2 = csr[p2];
                rowN = rowpos[p2];
                colN = ei[NE + e2];
            }
        }
        __syncthreads();                      // A + rad + rl ready

        // layer 1
        f32x4 acc[4];
#pragma unroll
        for (int rt = 0; rt < 4; rt++) {
#pragma unroll
            for (int r = 0; r < 4; r++)
                acc[rt][r] = fmaf(rad_lds[rt * 16 + hi * 4 + r], wl1, bj1);
        }
#pragma unroll
        for (int kc = 0; kc < 4; kc++) {
#pragma unroll
            for (int rt = 0; rt < 4; rt++) {
                int row = rt * 16 + lo;
                bf16x8 a = *(bf16x8*)(abase + ((row * 256 + kc * 64 + hi * 16) ^ ((row & 7) << 4)));
                acc[rt] = __builtin_amdgcn_mfma_f32_16x16x32_bf16(a, b1f[kc], acc[rt], 0, 0, 0);
            }
        }
#pragma unroll
        for (int rt = 0; rt < 4; rt++) {
#pragma unroll
            for (int r = 0; r < 4; r++) {
                int row = rt * 16 + hi * 4 + r;
                *(unsigned short*)(mbase + ((row * 128 + (wv * 16 + lo) * 2) ^ ((row & 7) << 4))) =
                    f2bf(lrelu(acc[rt][r]));
            }
        }
        __syncthreads();                      // M ready; Alds reads done

        // layer 2
        f32x4 acc2[4];
#pragma unroll
        for (int rt = 0; rt < 4; rt++) {
#pragma unroll
            for (int r = 0; r < 4; r++) acc2[rt][r] = bj2;
        }
#pragma unroll
        for (int kc = 0; kc < 2; kc++) {
#pragma unroll
            for (int rt = 0; rt < 4; rt++) {
                int row = rt * 16 + lo;
                bf16x8 a = *(bf16x8*)(mbase + ((row * 128 + kc * 64 + hi * 16) ^ ((row & 7) << 4)));
                acc2[rt] = __builtin_amdgcn_mfma_f32_16x16x32_bf16(a, b2f[kc], acc2[rt], 0, 0, 0);
            }
        }
        // lrelu -> fp32 out-tile in Alds (swizzled)
#pragma unroll
        for (int rt = 0; rt < 4; rt++) {
#pragma unroll
            for (int r = 0; r < 4; r++) {
                int row = rt * 16 + hi * 4 + r;
                *(float*)(abase + ((row * 256 + (wv * 16 + lo) * 4) ^ ((row & 7) << 4))) =
                    lrelu(acc2[rt][r]);
            }
        }
        __syncthreads();                      // out-tile ready

        // (a) edge_feat write-out: 4 threads per pos, 64B each, scattered full rows
        {
            int i = t >> 2, och = t & 3;
            int osw = (i & 7) << 4;
            int e = csr[blk * EPB + tl * 64 + i];
            uint4 o0 = *(uint4*)(abase + ((i * 256 + och * 64 +  0) ^ osw));
            uint4 o1 = *(uint4*)(abase + ((i * 256 + och * 64 + 16) ^ osw));
            uint4 o2 = *(uint4*)(abase + ((i * 256 + och * 64 + 32) ^ osw));
            uint4 o3 = *(uint4*)(abase + ((i * 256 + och * 64 + 48) ^ osw));
            uint4* dst = (uint4*)(edge_feat + (size_t)e * 64 + och * 16);
            dst[0] = o0; dst[1] = o1; dst[2] = o2; dst[3] = o3;
        }
        // (b) partial agg: wave wv scans pos window [wv*16,+16), lane = column
        {
            int i0 = wv * 16;
            int cur = rl_lds[i0];
            float s = *(float*)(abase + ((i0 * 256 + lane * 4) ^ ((i0 & 7) << 4)));
#pragma unroll
            for (int ii = 1; ii < 16; ii++) {
                int idx = i0 + ii;
                int r = rl_lds[idx];                 // wave-uniform
                float v = *(float*)(abase + ((idx * 256 + lane * 4) ^ ((idx & 7) << 4)));
                if (r != cur) {
                    atomicAdd(&agg[(size_t)cur * 64 + lane], s);
                    s = v; cur = r;
                } else {
                    s += v;
                }
            }
            atomicAdd(&agg[(size_t)cur * 64 + lane], s);
        }
    }
}

// ---------- node MLP (MFMA): streamed agg read, no gather ----------
__global__ __launch_bounds__(256) void agg_node_mfma(
    const unsigned short* __restrict__ hb, const float* __restrict__ h,
    const float* __restrict__ coord, const float* __restrict__ agg,
    const unsigned short* __restrict__ w1nt, const float* __restrict__ b1n,
    const unsigned short* __restrict__ w2nt, const float* __restrict__ b2n,
    float* __restrict__ h_out, float* __restrict__ coord_out)
{
    __shared__ unsigned short Alds[64 * 128];   // [hb | agg_bf16], swizzled
    __shared__ unsigned short Mlds[64 * 64];

    const int t = threadIdx.x, blk = blockIdx.x;
    const int lane = t & 63, wv = t >> 6;
    const int lo = lane & 15, hi = lane >> 4;
    const int nb = blk * 64;
    char* abase = (char*)Alds;
    char* mbase = (char*)Mlds;

    bf16x8 b1f[4], b2f[2];
#pragma unroll
    for (int kc = 0; kc < 4; kc++)
        b1f[kc] = *(const bf16x8*)(w1nt + (wv * 16 + lo) * 128 + kc * 32 + hi * 8);
#pragma unroll
    for (int kc = 0; kc < 2; kc++)
        b2f[kc] = *(const bf16x8*)(w2nt + (wv * 16 + lo) * 64 + kc * 32 + hi * 8);
    const float bj1 = b1n[wv * 16 + lo];
    const float bj2 = b2n[wv * 16 + lo];

    {   // stage hb rows -> A cols 0..63
        int row = t >> 2, seg = t & 3;
        int n = min(nb + row, NN - 1);
        const uint4* src = (const uint4*)(hb + (size_t)n * 64 + seg * 16);
        int base = row * 256 + seg * 32;
        int swr = (row & 7) << 4;
        uint4 v0 = src[0], v1 = src[1];
        *(uint4*)(abase + (base ^ swr)) = v0;
        *(uint4*)(abase + ((base + 16) ^ swr)) = v1;
    }
    {   // stage agg rows (fp32 -> bf16) -> A cols 64..127
        int row = t >> 2, seg = t & 3;
        int n = min(nb + row, NN - 1);
        const float4* asrc = (const float4*)(agg + (size_t)n * 64 + seg * 16);
        float4 a0 = asrc[0], a1 = asrc[1], a2 = asrc[2], a3 = asrc[3];
        unsigned int u0 = f2bf(a0.x) | ((unsigned)f2bf(a0.y) << 16);
        unsigned int u1 = f2bf(a0.z) | ((unsigned)f2bf(a0.w) << 16);
        unsigned int u2 = f2bf(a1.x) | ((unsigned)f2bf(a1.y) << 16);
        unsigned int u3 = f2bf(a1.z) | ((unsigned)f2bf(a1.w) << 16);
        unsigned int u4 = f2bf(a2.x) | ((unsigned)f2bf(a2.y) << 16);
        unsigned int u5 = f2bf(a2.z) | ((unsigned)f2bf(a2.w) << 16);
        unsigned int u6 = f2bf(a3.x) | ((unsigned)f2bf(a3.y) << 16);
        unsigned int u7 = f2bf(a3.z) | ((unsigned)f2bf(a3.w) << 16);
        int base = row * 256 + 128 + seg * 32;
        int swr = (row & 7) << 4;
        *(uint4*)(abase + (base ^ swr)) = make_uint4(u0, u1, u2, u3);
        *(uint4*)(abase + ((base + 16) ^ swr)) = make_uint4(u4, u5, u6, u7);
    }
    __syncthreads();

    // layer 1
    f32x4 acc[4];
#pragma unroll
    for (int rt = 0; rt < 4; rt++) {
#pragma unroll
        for (int r = 0; r < 4; r++) acc[rt][r] = bj1;
    }
#pragma unroll
    for (int kc = 0; kc < 4; kc++) {
#pragma unroll
        for (int rt = 0; rt < 4; rt++) {
            int row = rt * 16 + lo;
            bf16x8 a = *(bf16x8*)(abase + ((row * 256 + kc * 64 + hi * 16) ^ ((row & 7) << 4)));
            acc[rt] = __builtin_amdgcn_mfma_f32_16x16x32_bf16(a, b1f[kc], acc[rt], 0, 0, 0);
        }
    }
#pragma unroll
    for (int rt = 0; rt < 4; rt++) {
#pragma unroll
        for (int r = 0; r < 4; r++) {
            int row = rt * 16 + hi * 4 + r;
            *(unsigned short*)(mbase + ((row * 128 + (wv * 16 + lo) * 2) ^ ((row & 7) << 4))) =
                f2bf(lrelu(acc[rt][r]));
        }
    }
    __syncthreads();

    // layer 2 (no lrelu) + residual + store
    f32x4 acc2[4];
#pragma unroll
    for (int rt = 0; rt < 4; rt++) {
#pragma unroll
        for (int r = 0; r < 4; r++) acc2[rt][r] = bj2;
    }
#pragma unroll
    for (int kc = 0; kc < 2; kc++) {
#pragma unroll
        for (int rt = 0; rt < 4; rt++) {
            int row = rt * 16 + lo;
            bf16x8 a = *(bf16x8*)(mbase + ((row * 128 + kc * 64 + hi * 16) ^ ((row & 7) << 4)));
            acc2[rt] = __builtin_amdgcn_mfma_f32_16x16x32_bf16(a, b2f[kc], acc2[rt], 0, 0, 0);
        }
    }
#pragma unroll
    for (int rt = 0; rt < 4; rt++) {
#pragma unroll
        for (int r = 0; r < 4; r++) {
            int row = rt * 16 + hi * 4 + r;
            int n = nb + row;
            if (n < NN) {
                int c = wv * 16 + lo;
                h_out[(size_t)n * 64 + c] = h[(size_t)n * 64 + c] + acc2[rt][r];
            }
        }
    }

    if (t < 192) {
        int idx = nb * 3 + t;
        if (idx < NN * 3) coord_out[idx] = coord[idx];
    }
}

extern "C" void kernel_launch(void* const* d_in, const int* in_sizes, int n_in,
                              void* d_out, int out_size, void* d_ws, size_t ws_size,
                              hipStream_t stream)
{
    const float* h     = (const float*)d_in[0];
    const float* coord = (const float*)d_in[1];
    const int*   ei    = (const int*)d_in[2];
    const float* w1e   = (const float*)d_in[3];
    const float* b1e   = (const float*)d_in[4];
    const float* w2e   = (const float*)d_in[5];
    const float* b2e   = (const float*)d_in[6];
    const float* w1n   = (const float*)d_in[7];
    const float* b1n   = (const float*)d_in[8];
    const float* w2n   = (const float*)d_in[9];
    const float* b2n   = (const float*)d_in[10];

    float* out       = (float*)d_out;
    float* h_out     = out;                         // [N, 64]
    float* coord_out = out + (size_t)NN * D;        // [N, 3]
    float* edge_feat = coord_out + (size_t)NN * 3;  // [E, 64]

    char* ws = (char*)d_ws;
    unsigned short* hb   = (unsigned short*)ws;  ws += sizeof(unsigned short) * (size_t)NN * D;  // 6.4 MB
    unsigned short* w1t  = (unsigned short*)ws;  ws += sizeof(unsigned short) * 64 * 128;
    unsigned short* w2t  = (unsigned short*)ws;  ws += sizeof(unsigned short) * 64 * 64;
    unsigned short* w1nt = (unsigned short*)ws;  ws += sizeof(unsigned short) * 64 * 128;
    unsigned short* w2nt = (unsigned short*)ws;  ws += sizeof(unsigned short) * 64 * 64;
    float* agg  = (float*)ws;                    ws += sizeof(float) * (size_t)NN * D;           // 12.8 MB
    int* counts = (int*)ws;                      ws += sizeof(int) * NN;
    int* offs   = (int*)ws;                      ws += sizeof(int) * NN;
    int* cursor = (int*)ws;                      ws += sizeof(int) * NN;
    int* bsums  = (int*)ws;                      ws += sizeof(int) * 64;
    int* csr    = (int*)ws;                      ws += sizeof(int) * NE;                         // 3.2 MB
    int* rowpos = (int*)ws;                      ws += sizeof(int) * NE;                         // 3.2 MB

    hipMemsetAsync(counts, 0, sizeof(int) * NN, stream);
    hipMemsetAsync(agg, 0, sizeof(float) * (size_t)NN * D, stream);

    prep_count<<<NE / 256, 256, 0, stream>>>(h, hb, ei, counts,
                                             w1e, w2e, w1n, w2n, w1t, w2t, w1nt, w2nt);

    scan_block_kernel<<<NB, SCAN_B, 0, stream>>>(counts, offs, bsums);
    scan_top_kernel<<<1, 64, 0, stream>>>(bsums);
    add_back_kernel<<<NB, SCAN_B, 0, stream>>>(offs, bsums, cursor);
    scatter_kernel<<<(NE + 255) / 256, 256, 0, stream>>>(ei, cursor, csr, rowpos);

    egnn_edge_mfma<<<NE / EPB, 256, 0, stream>>>(
        hb, coord, ei, csr, rowpos, w1t, b1e, w1e, w2t, b2e, edge_feat, agg);

    agg_node_mfma<<<(NN + 63) / 64, 256, 0, stream>>>(
        hb, h, coord, agg, w1nt, b1n, w2nt, b2n, h_out, coord_out);
}